// Round 10
// baseline (556.550 us; speedup 1.0000x reference)
//
#include <hip/hip_runtime.h>
#include <hip/hip_bf16.h>

typedef __hip_bfloat16 bf16;
typedef __attribute__((ext_vector_type(8))) short short8;
typedef __attribute__((ext_vector_type(16))) float floatx16;
typedef __attribute__((address_space(3))) char c3;

template <int V> struct ic { static constexpr int value = V; };

__device__ __forceinline__ unsigned short f2bf(float x) {
  unsigned u = __builtin_bit_cast(unsigned, x);
  unsigned r = (u + 0x7fffu + ((u >> 16) & 1u)) >> 16;
  return (unsigned short)r;
}

#define GLL(g, l) __builtin_amdgcn_global_load_lds(                                  \
    (const __attribute__((address_space(1))) void*)(g),                              \
    (__attribute__((address_space(3))) void*)(l), 16, 0, 0)

template <int N> __device__ __forceinline__ void vmwait() {
  asm volatile("s_waitcnt vmcnt(%0)" ::"i"(N) : "memory");
}
template <int N> __device__ __forceinline__ void lgkwait() {
  asm volatile("s_waitcnt lgkmcnt(%0)" ::"i"(N) : "memory");
  __builtin_amdgcn_sched_barrier(0);
}
template <int OFF> __device__ __forceinline__ short8 dsr(unsigned a) {
  short8 r;
  asm volatile("ds_read_b128 %0, %1 offset:%2" : "=v"(r) : "v"(a), "i"(OFF));
  return r;
}
#define MFMA32(d, a, b) d = __builtin_amdgcn_mfma_f32_32x32x16_bf16(a, b, d, 0, 0, 0)

// ---------------- weight transpose+convert: fp32 [K][N] -> bf16 [N][K] ----------
__global__ __launch_bounds__(256) void wtrans_kernel(const float* __restrict__ in,
                                                     bf16* __restrict__ out,
                                                     int K, int N) {
  __shared__ float tile[32][33];
  int tx = threadIdx.x, ty = threadIdx.y;
  int n0 = blockIdx.x * 32, k0 = blockIdx.y * 32;
#pragma unroll
  for (int i = 0; i < 32; i += 8)
    tile[ty + i][tx] = in[(size_t)(k0 + ty + i) * N + (n0 + tx)];
  __syncthreads();
#pragma unroll
  for (int i = 0; i < 32; i += 8)
    out[(size_t)(n0 + ty + i) * K + (k0 + tx)] = __float2bfloat16(tile[tx][ty + i]);
}

// ---------------- LayerNorm fp32 -> bf16, D=1024, one block(256)/row ------------
__global__ __launch_bounds__(256) void ln_kernel(const float* __restrict__ x,
                                                 const float* __restrict__ g,
                                                 const float* __restrict__ b,
                                                 bf16* __restrict__ out) {
  const int D = 1024;
  size_t row = blockIdx.x;
  int t = threadIdx.x;
  float4 v = ((const float4*)(x + row * D))[t];
  float s  = v.x + v.y + v.z + v.w;
  float ss = v.x * v.x + v.y * v.y + v.z * v.z + v.w * v.w;
#pragma unroll
  for (int off = 32; off > 0; off >>= 1) {
    s  += __shfl_xor(s, off);
    ss += __shfl_xor(ss, off);
  }
  __shared__ float rs[4], rss[4];
  int wv = t >> 6;
  if ((t & 63) == 0) { rs[wv] = s; rss[wv] = ss; }
  __syncthreads();
  s  = rs[0] + rs[1] + rs[2] + rs[3];
  ss = rss[0] + rss[1] + rss[2] + rss[3];
  float mu  = s * (1.f / D);
  float inv = rsqrtf(ss * (1.f / D) - mu * mu + 1e-5f);
  float4 gv = ((const float4*)g)[t];
  float4 bv = ((const float4*)b)[t];
  ushort4 o;
  o.x = f2bf((v.x - mu) * inv * gv.x + bv.x);
  o.y = f2bf((v.y - mu) * inv * gv.y + bv.y);
  o.z = f2bf((v.z - mu) * inv * gv.z + bv.z);
  o.w = f2bf((v.w - mu) * inv * gv.w + bv.w);
  ((ushort4*)(out + row * D))[t] = o;
}

// ---------------- softmax: fp32 row (2048) -> bf16 written in place -------------
__global__ __launch_bounds__(256) void softmax_kernel(float* sc) {
  const int S = 2048;
  float* p = sc + (size_t)blockIdx.x * S;
  int t = threadIdx.x;
  float4 v0 = ((const float4*)p)[2 * t];
  float4 v1 = ((const float4*)p)[2 * t + 1];
  float f[8] = {v0.x, v0.y, v0.z, v0.w, v1.x, v1.y, v1.z, v1.w};
  float m = f[0];
#pragma unroll
  for (int j = 1; j < 8; ++j) m = fmaxf(m, f[j]);
#pragma unroll
  for (int off = 32; off > 0; off >>= 1) m = fmaxf(m, __shfl_xor(m, off));
  __shared__ float r1[4], r2[4];
  int wv = t >> 6;
  if ((t & 63) == 0) r1[wv] = m;
  __syncthreads();
  m = fmaxf(fmaxf(r1[0], r1[1]), fmaxf(r1[2], r1[3]));
  float s = 0.f;
#pragma unroll
  for (int j = 0; j < 8; ++j) { f[j] = __expf(f[j] - m); s += f[j]; }
#pragma unroll
  for (int off = 32; off > 0; off >>= 1) s += __shfl_xor(s, off);
  if ((t & 63) == 0) r2[wv] = s;
  __syncthreads();
  s = r2[0] + r2[1] + r2[2] + r2[3];
  float inv = 1.f / s;
  unsigned u0 = f2bf(f[0] * inv), u1 = f2bf(f[1] * inv);
  unsigned u2 = f2bf(f[2] * inv), u3 = f2bf(f[3] * inv);
  unsigned u4 = f2bf(f[4] * inv), u5 = f2bf(f[5] * inv);
  unsigned u6 = f2bf(f[6] * inv), u7 = f2bf(f[7] * inv);
  uint4 o;
  o.x = u0 | (u1 << 16);
  o.y = u2 | (u3 << 16);
  o.z = u4 | (u5 << 16);
  o.w = u6 | (u7 << 16);
  ((uint4*)p)[t] = o;
}

// ======= 32x32x16-MFMA GEMM, BN=256 (gemmA): BM=256, BK=64, 8 waves (2Mx4N) =====
// Per-wave output 128x64: acc[4][2] f32x16 (128 AGPR). 2 phases/K-tile (k-halves
// of 32), each: {12 ds_read_b128 | stage one k-half group (4 GLL) | lgkm0 |
// 16 MFMA 32x32x16 | counted vmcnt(8) | barrier}. K-half slabs = [256 rows][64B]
// contiguous 16KB, double-buffered (A 64KB + B 64KB = 128KB). Swizzle: 4-chunk
// XOR (chunk ^ (row&3)); source pre-swizzled, read s=1 via addr^32. vmcnt ledger
// (groups of 4): prologue k0(0),k1(0),k0(1) wait(8); steady mid/end wait(8)
// (1.5-tile lead, never 0); tails: nk-2 {8,4}, nk-1 {0,-}.
template <bool OUT_BF16, bool HAS_BIAS, bool HAS_RES, bool GELU, bool VTR>
__global__ __launch_bounds__(512, 2) void gemmA(
    const bf16* __restrict__ A, int lda, size_t sA,
    const bf16* __restrict__ BT, int ldb, size_t sB,
    void* Cv, size_t sC,
    const float* __restrict__ bias, const float* res, bf16* vtr,
    int N, int K, float alpha, int gx, int gy) {
  __shared__ __align__(16) char ldsb[131072];
  const unsigned lds0 = (unsigned)(uintptr_t)(c3*)ldsb;
  const unsigned ldsB0 = lds0 + 65536;

  const int tid = threadIdx.x;
  const int lane = tid & 63;
  const int wave = tid >> 6;
  const int wm = wave >> 2, wn = wave & 3;
  const int l5 = lane >> 5, l31 = lane & 31;

  int id = blockIdx.x;
  const int nwg = gridDim.x;
  if ((nwg & 7) == 0) id = (id & 7) * (nwg >> 3) + (id >> 3);  // XCD swizzle
  const int bx = id % gx;
  const int rem = id / gx;
  const int by = rem % gy;
  const int bz = rem / gy;
  const int m0 = by * 256, n0 = bx * 256;

  // staging: thread -> (row = tid>>2, 16B chunk = tid&3 within a 64B k-half);
  // source chunk pre-swizzled: LDS slot (r,cs) holds global chunk cs^(r&3)
  const int sr = tid >> 2;
  const int scc = ((tid & 3) ^ (sr & 3)) * 8;
  const bf16* gA = A + sA * bz + (size_t)(m0 + sr) * lda + scc;
  const bf16* gB = BT + sB * bz + (size_t)(n0 + sr) * ldb + scc;
  const int nk = K >> 6;

  auto stA = [&](int tt, int kh) {
    if (tt < nk) {
      const bf16* s = gA + (size_t)tt * 64 + kh * 32;
      char* d = ldsb + (((tt & 1) * 2 + kh) << 14) + tid * 16;
      GLL(s, d);
      GLL(s + (size_t)128 * lda, d + 8192);
    }
  };
  auto stB = [&](int tt, int kh) {
    if (tt < nk) {
      const bf16* s = gB + (size_t)tt * 64 + kh * 32;
      char* d = ldsb + 65536 + (((tt & 1) * 2 + kh) << 14) + tid * 16;
      GLL(s, d);
      GLL(s + (size_t)128 * ldb, d + 8192);
    }
  };

  // read addressing: row = frag-row (l&31), k-group g = l>>5; slot chunk =
  // (s*2+g) ^ (row&3) -> addr = rowbase + ((g^(l&3))<<4), s=1 via ^32
  const unsigned uswz = (unsigned)((l5 ^ (lane & 3)) << 4);
  const unsigned aRow = (unsigned)((wm * 128 + l31) * 64) + uswz;
  const unsigned bRow = (unsigned)((wn * 64 + l31) * 64) + uswz;

  floatx16 acc[4][2] = {};

  // prologue: groups k0(0), k1(0), k0(1); retire k0(0)
  stA(0, 0); stB(0, 0);
  stA(0, 1); stB(0, 1);
  stA(1, 0); stB(1, 0);
  vmwait<8>();
  __builtin_amdgcn_s_barrier();

  auto body = [&](int kt, auto modeC) {
    constexpr int MODE = decltype(modeC)::value;  // 0 steady, 1 = nk-2, 2 = nk-1
    const unsigned p = (unsigned)(kt & 1);
    const unsigned Ak0 = lds0 + ((p * 2 + 0) << 14);
    const unsigned Ak1 = lds0 + ((p * 2 + 1) << 14);
    const unsigned Bk0 = ldsB0 + ((p * 2 + 0) << 14);
    const unsigned Bk1 = ldsB0 + ((p * 2 + 1) << 14);
    short8 a0[4], a1[4], b0[2], b1[2];

    // ===== ph0: k-half 0; stage k1(kt+1)
    {
      const unsigned aA = Ak0 + aRow, aX = aA ^ 32;
      a0[0] = dsr<0>(aA); a0[1] = dsr<2048>(aA); a0[2] = dsr<4096>(aA); a0[3] = dsr<6144>(aA);
      a1[0] = dsr<0>(aX); a1[1] = dsr<2048>(aX); a1[2] = dsr<4096>(aX); a1[3] = dsr<6144>(aX);
      const unsigned bA = Bk0 + bRow, bX = bA ^ 32;
      b0[0] = dsr<0>(bA); b0[1] = dsr<2048>(bA);
      b1[0] = dsr<0>(bX); b1[1] = dsr<2048>(bX);
    }
    stA(kt + 1, 1); stB(kt + 1, 1);
    lgkwait<0>();
    __builtin_amdgcn_s_setprio(1);
#pragma unroll
    for (int mf = 0; mf < 4; ++mf)
#pragma unroll
      for (int nf = 0; nf < 2; ++nf) MFMA32(acc[mf][nf], a0[mf], b0[nf]);
#pragma unroll
    for (int mf = 0; mf < 4; ++mf)
#pragma unroll
      for (int nf = 0; nf < 2; ++nf) MFMA32(acc[mf][nf], a1[mf], b1[nf]);
    __builtin_amdgcn_s_setprio(0);
    if constexpr (MODE < 2) vmwait<8>();
    else vmwait<0>();
    __builtin_amdgcn_s_barrier();

    // ===== ph1: k-half 1; stage k0(kt+2)
    {
      const unsigned aA = Ak1 + aRow, aX = aA ^ 32;
      a0[0] = dsr<0>(aA); a0[1] = dsr<2048>(aA); a0[2] = dsr<4096>(aA); a0[3] = dsr<6144>(aA);
      a1[0] = dsr<0>(aX); a1[1] = dsr<2048>(aX); a1[2] = dsr<4096>(aX); a1[3] = dsr<6144>(aX);
      const unsigned bA = Bk1 + bRow, bX = bA ^ 32;
      b0[0] = dsr<0>(bA); b0[1] = dsr<2048>(bA);
      b1[0] = dsr<0>(bX); b1[1] = dsr<2048>(bX);
    }
    stA(kt + 2, 0); stB(kt + 2, 0);
    lgkwait<0>();
    __builtin_amdgcn_s_setprio(1);
#pragma unroll
    for (int mf = 0; mf < 4; ++mf)
#pragma unroll
      for (int nf = 0; nf < 2; ++nf) MFMA32(acc[mf][nf], a0[mf], b0[nf]);
#pragma unroll
    for (int mf = 0; mf < 4; ++mf)
#pragma unroll
      for (int nf = 0; nf < 2; ++nf) MFMA32(acc[mf][nf], a1[mf], b1[nf]);
    __builtin_amdgcn_s_setprio(0);
    if constexpr (MODE == 0) { vmwait<8>(); __builtin_amdgcn_s_barrier(); }
    else if constexpr (MODE == 1) { vmwait<4>(); __builtin_amdgcn_s_barrier(); }
  };

  for (int kt = 0; kt + 2 < nk; ++kt) body(kt, ic<0>{});
  body(nk - 2, ic<1>{});
  body(nk - 1, ic<2>{});

  // epilogue: 32x32 C/D map col=lane&31, row=(r&3)+8*(r>>2)+4*(lane>>5) [m74/m101]
  float* Cf = (float*)Cv;
  bf16* Cb = (bf16*)Cv;
  const size_t cb = sC * bz;
  const int colb = n0 + wn * 64 + l31;
  const int rowb = m0 + wm * 128 + (l5 << 2);
#pragma unroll
  for (int mf = 0; mf < 4; ++mf)
#pragma unroll
    for (int nf = 0; nf < 2; ++nf) {
      const int col = colb + nf * 32;
      const float bb = HAS_BIAS ? bias[col] : 0.f;
#pragma unroll
      for (int r = 0; r < 16; ++r) {
        const int row = rowb + mf * 32 + (r & 3) + ((r >> 2) << 3);
        float val = acc[mf][nf][r] * alpha + bb;
        if (GELU) val = 0.5f * val * (1.f + erff(val * 0.70710678118654752f));
        if (HAS_RES) val += res[(size_t)row * N + col];
        const size_t idx = cb + (size_t)row * N + col;
        if (OUT_BF16) Cb[idx] = __float2bfloat16(val);
        else Cf[idx] = val;
        if (VTR) {
          if (col >= 2048) {  // V cols: also write V^T [b][col-2048][row%S]
            vtr[(((size_t)(row >> 11) << 10) + (col - 2048)) * 2048 + (row & 2047)] =
                __float2bfloat16(val);
          }
        }
      }
    }
}

// ======= 32x32x16-MFMA GEMM, BN=128 (gemmB): per-wave 128x32, 96KB LDS ==========
// acc[4] f32x16 (64 AGPR). Same 2-phase structure; group = 3 GLL (2A+1B);
// steady mid/end vmcnt(6); tails: nk-2 {6,3}, nk-1 {0,-}.
template <bool OUT_BF16, bool HAS_BIAS, bool HAS_RES, bool GELU>
__global__ __launch_bounds__(512, 2) void gemmB(
    const bf16* __restrict__ A, int lda, size_t sA,
    const bf16* __restrict__ BT, int ldb, size_t sB,
    void* Cv, size_t sC,
    const float* __restrict__ bias, const float* res,
    int N, int K, float alpha, int gx, int gy) {
  __shared__ __align__(16) char ldsb[98304];
  const unsigned lds0 = (unsigned)(uintptr_t)(c3*)ldsb;
  const unsigned ldsB0 = lds0 + 65536;

  const int tid = threadIdx.x;
  const int lane = tid & 63;
  const int wave = tid >> 6;
  const int wm = wave >> 2, wn = wave & 3;
  const int l5 = lane >> 5, l31 = lane & 31;

  int id = blockIdx.x;
  const int nwg = gridDim.x;
  if ((nwg & 7) == 0) id = (id & 7) * (nwg >> 3) + (id >> 3);
  const int bx = id % gx;
  const int rem = id / gx;
  const int by = rem % gy;
  const int bz = rem / gy;
  const int m0 = by * 256, n0 = bx * 128;

  const int sr = tid >> 2;
  const int scc = ((tid & 3) ^ (sr & 3)) * 8;
  const bf16* gA = A + sA * bz + (size_t)(m0 + sr) * lda + scc;
  const bf16* gB = BT + sB * bz + (size_t)(n0 + sr) * ldb + scc;
  const int nk = K >> 6;

  auto stA = [&](int tt, int kh) {
    if (tt < nk) {
      const bf16* s = gA + (size_t)tt * 64 + kh * 32;
      char* d = ldsb + (((tt & 1) * 2 + kh) << 14) + tid * 16;
      GLL(s, d);
      GLL(s + (size_t)128 * lda, d + 8192);
    }
  };
  auto stB = [&](int tt, int kh) {  // 128 rows -> one 8KB pass
    if (tt < nk) {
      const bf16* s = gB + (size_t)tt * 64 + kh * 32;
      char* d = ldsb + 65536 + (((tt & 1) * 2 + kh) << 13) + tid * 16;
      GLL(s, d);
    }
  };

  const unsigned uswz = (unsigned)((l5 ^ (lane & 3)) << 4);
  const unsigned aRow = (unsigned)((wm * 128 + l31) * 64) + uswz;
  const unsigned bRow = (unsigned)((wn * 32 + l31) * 64) + uswz;

  floatx16 acc[4] = {};

  stA(0, 0); stB(0, 0);
  stA(0, 1); stB(0, 1);
  stA(1, 0); stB(1, 0);
  vmwait<6>();
  __builtin_amdgcn_s_barrier();

  auto body = [&](int kt, auto modeC) {
    constexpr int MODE = decltype(modeC)::value;
    const unsigned p = (unsigned)(kt & 1);
    const unsigned Ak0 = lds0 + ((p * 2 + 0) << 14);
    const unsigned Ak1 = lds0 + ((p * 2 + 1) << 14);
    const unsigned Bk0 = ldsB0 + ((p * 2 + 0) << 13);
    const unsigned Bk1 = ldsB0 + ((p * 2 + 1) << 13);
    short8 a0[4], a1[4], b0, b1;

    // ph0
    {
      const unsigned aA = Ak0 + aRow, aX = aA ^ 32;
      a0[0] = dsr<0>(aA); a0[1] = dsr<2048>(aA); a0[2] = dsr<4096>(aA); a0[3] = dsr<6144>(aA);
      a1[0] = dsr<0>(aX); a1[1] = dsr<2048>(aX); a1[2] = dsr<4096>(aX); a1[3] = dsr<6144>(aX);
      const unsigned bA = Bk0 + bRow;
      b0 = dsr<0>(bA); b1 = dsr<0>(bA ^ 32);
    }
    stA(kt + 1, 1); stB(kt + 1, 1);
    lgkwait<0>();
    __builtin_amdgcn_s_setprio(1);
#pragma unroll
    for (int mf = 0; mf < 4; ++mf) MFMA32(acc[mf], a0[mf], b0);
#pragma unroll
    for (int mf = 0; mf < 4; ++mf) MFMA32(acc[mf], a1[mf], b1);
    __builtin_amdgcn_s_setprio(0);
    if constexpr (MODE < 2) vmwait<6>();
    else vmwait<0>();
    __builtin_amdgcn_s_barrier();

    // ph1
    {
      const unsigned aA = Ak1 + aRow, aX = aA ^ 32;
      a0[0] = dsr<0>(aA); a0[1] = dsr<2048>(aA); a0[2] = dsr<4096>(aA); a0[3] = dsr<6144>(aA);
      a1[0] = dsr<0>(aX); a1[1] = dsr<2048>(aX); a1[2] = dsr<4096>(aX); a1[3] = dsr<6144>(aX);
      const unsigned bA = Bk1 + bRow;
      b0 = dsr<0>(bA); b1 = dsr<0>(bA ^ 32);
    }
    stA(kt + 2, 0); stB(kt + 2, 0);
    lgkwait<0>();
    __builtin_amdgcn_s_setprio(1);
#pragma unroll
    for (int mf = 0; mf < 4; ++mf) MFMA32(acc[mf], a0[mf], b0);
#pragma unroll
    for (int mf = 0; mf < 4; ++mf) MFMA32(acc[mf], a1[mf], b1);
    __builtin_amdgcn_s_setprio(0);
    if constexpr (MODE == 0) { vmwait<6>(); __builtin_amdgcn_s_barrier(); }
    else if constexpr (MODE == 1) { vmwait<3>(); __builtin_amdgcn_s_barrier(); }
  };

  for (int kt = 0; kt + 2 < nk; ++kt) body(kt, ic<0>{});
  body(nk - 2, ic<1>{});
  body(nk - 1, ic<2>{});

  float* Cf = (float*)Cv;
  bf16* Cb = (bf16*)Cv;
  const size_t cb = sC * bz;
  const int col = n0 + wn * 32 + l31;
  const int rowb = m0 + wm * 128 + (l5 << 2);
  const float bb = HAS_BIAS ? bias[col] : 0.f;
#pragma unroll
  for (int mf = 0; mf < 4; ++mf)
#pragma unroll
    for (int r = 0; r < 16; ++r) {
      const int row = rowb + mf * 32 + (r & 3) + ((r >> 2) << 3);
      float val = acc[mf][r] * alpha + bb;
      if (GELU) val = 0.5f * val * (1.f + erff(val * 0.70710678118654752f));
      if (HAS_RES) val += res[(size_t)row * N + col];
      const size_t idx = cb + (size_t)row * N + col;
      if (OUT_BF16) Cb[idx] = __float2bfloat16(val);
      else Cf[idx] = val;
    }
}

extern "C" void kernel_launch(void* const* d_in, const int* in_sizes, int n_in,
                              void* d_out, int out_size, void* d_ws, size_t ws_size,
                              hipStream_t stream) {
  const int B = 4, S = 2048, D = 1024, DFF = 4096;
  const int M = B * S;
  const float* x   = (const float*)d_in[0];
  const float* wq  = (const float*)d_in[1];
  const float* bq  = (const float*)d_in[2];
  const float* wk  = (const float*)d_in[3];
  const float* bk  = (const float*)d_in[4];
  const float* wv  = (const float*)d_in[5];
  const float* bv  = (const float*)d_in[6];
  const float* wo  = (const float*)d_in[7];
  const float* bo  = (const float*)d_in[8];
  const float* w1  = (const float*)d_in[9];
  const float* b1  = (const float*)d_in[10];
  const float* w2  = (const float*)d_in[11];
  const float* b2  = (const float*)d_in[12];
  const float* g1  = (const float*)d_in[13];
  const float* be1 = (const float*)d_in[14];
  const float* g2  = (const float*)d_in[15];
  const float* be2 = (const float*)d_in[16];
  float* out = (float*)d_out;

  // workspace arena:
  //  0-6 wqkvT  6-8 woT  8-16 w1T  16-24 w2T  24 bqkv  25-41 h (bf16 MxD)
  //  41-89 qkv (bf16 Mx3072) / later hidden (bf16 MxDFF, 41-105)
  //  89-105 vT [4][D][S] bf16 (written by QKV epilogue)
  //  105+  scores fp32, chunk*16MB
  char* wsb = (char*)d_ws;
  const size_t MB1 = 1ull << 20;
  bf16* wqkvT = (bf16*)(wsb + 0 * MB1);
  bf16* woT   = (bf16*)(wsb + 6 * MB1);
  bf16* w1T   = (bf16*)(wsb + 8 * MB1);
  bf16* w2T   = (bf16*)(wsb + 16 * MB1);
  float* bqkv = (float*)(wsb + 24 * MB1);
  bf16* h     = (bf16*)(wsb + 25 * MB1);
  bf16* qkv   = (bf16*)(wsb + 41 * MB1);
  bf16* hidden = (bf16*)(wsb + 41 * MB1);
  bf16* vTall = (bf16*)(wsb + 89 * MB1);
  float* sc   = (float*)(wsb + 105 * MB1);

  int chunk = 1;
  if (ws_size > 105 * MB1) {
    size_t c = (ws_size - 105 * MB1) / (16 * MB1);
    chunk = (int)(c > 4 ? 4 : (c < 1 ? 1 : c));
  }

  dim3 tb(32, 8);
  wtrans_kernel<<<dim3(32, 32), tb, 0, stream>>>(wq, wqkvT, D, D);
  wtrans_kernel<<<dim3(32, 32), tb, 0, stream>>>(wk, wqkvT + (size_t)1024 * 1024, D, D);
  wtrans_kernel<<<dim3(32, 32), tb, 0, stream>>>(wv, wqkvT + (size_t)2048 * 1024, D, D);
  wtrans_kernel<<<dim3(32, 32), tb, 0, stream>>>(wo, woT, D, D);
  wtrans_kernel<<<dim3(128, 32), tb, 0, stream>>>(w1, w1T, D, DFF);
  wtrans_kernel<<<dim3(32, 128), tb, 0, stream>>>(w2, w2T, DFF, D);
  hipMemcpyAsync(bqkv, bq, 4096, hipMemcpyDeviceToDevice, stream);
  hipMemcpyAsync(bqkv + 1024, bk, 4096, hipMemcpyDeviceToDevice, stream);
  hipMemcpyAsync(bqkv + 2048, bv, 4096, hipMemcpyDeviceToDevice, stream);

  // h = LN1(x)
  ln_kernel<<<M, 256, 0, stream>>>(x, g1, be1, h);

  // qkv = h @ [wq|wk|wv] + biases; V cols also emitted transposed into vTall
  gemmA<true, true, false, false, true><<<12 * 32, 512, 0, stream>>>(
      h, D, 0, wqkvT, D, 0, qkv, 0, bqkv, nullptr, vTall, 3072, D, 1.f, 12, 32);

  for (int b0 = 0; b0 < B; b0 += chunk) {
    int c = (B - b0 < chunk) ? (B - b0) : chunk;
    // scores = q @ k^T * 0.125 (fp32)
    gemmA<false, false, false, false, false><<<64 * c, 512, 0, stream>>>(
        qkv + (size_t)b0 * S * 3072, 3072, (size_t)S * 3072,
        qkv + (size_t)b0 * S * 3072 + 1024, 3072, (size_t)S * 3072,
        sc, (size_t)S * S, nullptr, nullptr, nullptr, S, D, 0.125f, 8, 8);
    softmax_kernel<<<c * S, 256, 0, stream>>>(sc);
    // ctx = probs @ vT^T (probs bf16 in-place over fp32 rows, pitch 2S)
    gemmB<true, false, false, false><<<64 * c, 512, 0, stream>>>(
        (const bf16*)sc, 2 * S, (size_t)S * 2 * S,
        vTall + (size_t)b0 * D * S, S, (size_t)D * S,
        h + (size_t)b0 * S * D, (size_t)S * D, nullptr, nullptr, D, S, 1.f, 8, 8);
  }

  // x2 = ctx @ wo + bo + x -> d_out (fp32)
  gemmB<false, true, true, false><<<8 * 32, 512, 0, stream>>>(
      h, D, 0, woT, D, 0, out, 0, bo, x, D, D, 1.f, 8, 32);

  // h = LN2(x2)
  ln_kernel<<<M, 256, 0, stream>>>(out, g2, be2, h);

  // hidden = gelu(h @ w1 + b1)
  gemmA<true, true, false, true, false><<<16 * 32, 512, 0, stream>>>(
      h, D, 0, w1T, D, 0, hidden, 0, b1, nullptr, nullptr, DFF, D, 1.f, 16, 32);

  // out = hidden @ w2 + b2 + x2 (in-place residual)
  gemmB<false, true, true, false><<<8 * 32, 512, 0, stream>>>(
      hidden, DFF, 0, w2T, DFF, 0, out, 0, b2, out, D, DFF, 1.f, 8, 32);
}

// Round 11
// 509.394 us; speedup vs baseline: 1.0926x; 1.0926x over previous
//
#include <hip/hip_runtime.h>
#include <hip/hip_bf16.h>

typedef __hip_bfloat16 bf16;
typedef __attribute__((ext_vector_type(8))) short short8;
typedef __attribute__((ext_vector_type(4))) float floatx4;

__device__ __forceinline__ unsigned short f2bf(float x) {
  unsigned u = __builtin_bit_cast(unsigned, x);
  unsigned r = (u + 0x7fffu + ((u >> 16) & 1u)) >> 16;
  return (unsigned short)r;
}

#define GLL(g, l) __builtin_amdgcn_global_load_lds(                                  \
    (const __attribute__((address_space(1))) void*)(g),                              \
    (__attribute__((address_space(3))) void*)(l), 16, 0, 0)

// ---------------- weight transpose+convert: fp32 [K][N] -> bf16 [N][K] ----------
__global__ __launch_bounds__(256) void wtrans_kernel(const float* __restrict__ in,
                                                     bf16* __restrict__ out,
                                                     int K, int N) {
  __shared__ float tile[32][33];
  int tx = threadIdx.x, ty = threadIdx.y;
  int n0 = blockIdx.x * 32, k0 = blockIdx.y * 32;
#pragma unroll
  for (int i = 0; i < 32; i += 8)
    tile[ty + i][tx] = in[(size_t)(k0 + ty + i) * N + (n0 + tx)];
  __syncthreads();
#pragma unroll
  for (int i = 0; i < 32; i += 8)
    out[(size_t)(n0 + ty + i) * K + (k0 + tx)] = __float2bfloat16(tile[tx][ty + i]);
}

// ---------------- LayerNorm fp32 -> bf16, D=1024, one block(256)/row ------------
__global__ __launch_bounds__(256) void ln_kernel(const float* __restrict__ x,
                                                 const float* __restrict__ g,
                                                 const float* __restrict__ b,
                                                 bf16* __restrict__ out) {
  const int D = 1024;
  size_t row = blockIdx.x;
  int t = threadIdx.x;
  float4 v = ((const float4*)(x + row * D))[t];
  float s  = v.x + v.y + v.z + v.w;
  float ss = v.x * v.x + v.y * v.y + v.z * v.z + v.w * v.w;
#pragma unroll
  for (int off = 32; off > 0; off >>= 1) {
    s  += __shfl_xor(s, off);
    ss += __shfl_xor(ss, off);
  }
  __shared__ float rs[4], rss[4];
  int wv = t >> 6;
  if ((t & 63) == 0) { rs[wv] = s; rss[wv] = ss; }
  __syncthreads();
  s  = rs[0] + rs[1] + rs[2] + rs[3];
  ss = rss[0] + rss[1] + rss[2] + rss[3];
  float mu  = s * (1.f / D);
  float inv = rsqrtf(ss * (1.f / D) - mu * mu + 1e-5f);
  float4 gv = ((const float4*)g)[t];
  float4 bv = ((const float4*)b)[t];
  ushort4 o;
  o.x = f2bf((v.x - mu) * inv * gv.x + bv.x);
  o.y = f2bf((v.y - mu) * inv * gv.y + bv.y);
  o.z = f2bf((v.z - mu) * inv * gv.z + bv.z);
  o.w = f2bf((v.w - mu) * inv * gv.w + bv.w);
  ((ushort4*)(out + row * D))[t] = o;
}

// ---------------- softmax: fp32 row (2048) -> bf16 written in place -------------
__global__ __launch_bounds__(256) void softmax_kernel(float* sc) {
  const int S = 2048;
  float* p = sc + (size_t)blockIdx.x * S;
  int t = threadIdx.x;
  float4 v0 = ((const float4*)p)[2 * t];
  float4 v1 = ((const float4*)p)[2 * t + 1];
  float f[8] = {v0.x, v0.y, v0.z, v0.w, v1.x, v1.y, v1.z, v1.w};
  float m = f[0];
#pragma unroll
  for (int j = 1; j < 8; ++j) m = fmaxf(m, f[j]);
#pragma unroll
  for (int off = 32; off > 0; off >>= 1) m = fmaxf(m, __shfl_xor(m, off));
  __shared__ float r1[4], r2[4];
  int wv = t >> 6;
  if ((t & 63) == 0) r1[wv] = m;
  __syncthreads();
  m = fmaxf(fmaxf(r1[0], r1[1]), fmaxf(r1[2], r1[3]));
  float s = 0.f;
#pragma unroll
  for (int j = 0; j < 8; ++j) { f[j] = __expf(f[j] - m); s += f[j]; }
#pragma unroll
  for (int off = 32; off > 0; off >>= 1) s += __shfl_xor(s, off);
  if ((t & 63) == 0) r2[wv] = s;
  __syncthreads();
  s = r2[0] + r2[1] + r2[2] + r2[3];
  float inv = 1.f / s;
  unsigned u0 = f2bf(f[0] * inv), u1 = f2bf(f[1] * inv);
  unsigned u2 = f2bf(f[2] * inv), u3 = f2bf(f[3] * inv);
  unsigned u4 = f2bf(f[4] * inv), u5 = f2bf(f[5] * inv);
  unsigned u6 = f2bf(f[6] * inv), u7 = f2bf(f[7] * inv);
  uint4 o;
  o.x = u0 | (u1 << 16);
  o.y = u2 | (u3 << 16);
  o.z = u4 | (u5 << 16);
  o.w = u6 | (u7 << 16);
  ((uint4*)p)[t] = o;
}

// ---------------- m97-style GEMM: 128x128, BK=32, 4 waves, dbuf 32KB LDS --------
// C = alpha*(A[M,K] @ BT[N,K]^T) (+bias)(+gelu)(+res). Multi-block/CU overlap
// (launch_bounds(256,3) -> 12 waves/CU): barrier drains hidden by other blocks
// (m114). Plain C++ ds_reads (compiler-managed waitcnts). LDS swizzle for 64B
// rows: physChunk = logicalChunk ^ ((row>>1)&3) -- balanced 8 lanes/bank-group
// (the r10 (row&3) variant was 8-way-conflicted). Source pre-swizzled so linear
// GLL dest + XOR'd read are consistent (rule #21).
template <bool OUT_BF16, bool HAS_BIAS, bool HAS_RES, bool GELU, bool VTR>
__global__ __launch_bounds__(256, 3) void gemmT(
    const bf16* __restrict__ A, int lda, size_t sA,
    const bf16* __restrict__ BT, int ldb, size_t sB,
    void* Cv, size_t sC,
    const float* __restrict__ bias, const float* res, bf16* vtr,
    int N, int K, float alpha, int gx, int gy) {
  __shared__ bf16 As[2][128 * 32];
  __shared__ bf16 Bs[2][128 * 32];
  const int tid = threadIdx.x;
  const int wave = tid >> 6, lane = tid & 63;
  const int lr = lane & 15, lq = lane >> 4;
  const int wm = wave >> 1, wn = wave & 1;

  int id = blockIdx.x;
  const int nwg = gridDim.x;
  if ((nwg & 7) == 0) id = (id & 7) * (nwg >> 3) + (id >> 3);  // XCD swizzle
  const int bx = id % gx;
  const int rem = id / gx;
  const int by = rem % gy;
  const int bz = rem / gy;
  const int m0 = by * 128, n0 = bx * 128;

  // staging: thread -> (row = tid>>2 [+64 for 2nd GLL], chunk = tid&3);
  // source chunk pre-swizzled with f(row) = (row>>1)&3 = (tid>>3)&3
  const int srow = tid >> 2;
  const int scc = ((tid & 3) ^ ((tid >> 3) & 3)) * 8;
  const bf16* ga = A + sA * bz + (size_t)(m0 + srow) * lda + scc;
  const bf16* gb = BT + sB * bz + (size_t)(n0 + srow) * ldb + scc;
  bf16* la = &As[0][0] + tid * 8;  // linear LDS dest (wave-uniform base + lane*16B)
  bf16* lb = &Bs[0][0] + tid * 8;

  floatx4 acc[4][4] = {};
  const int nk = K >> 5;

  // prologue: stage k-tile 0 into buffer 0
  GLL(ga, la);
  GLL(ga + (size_t)64 * lda, la + 64 * 32);
  GLL(gb, lb);
  GLL(gb + (size_t)64 * ldb, lb + 64 * 32);
  __syncthreads();

  // read: row = w*64 + i*16 + lr; f(row) = (lr>>1)&3 (other terms = 0 mod 4)
  const int fsw = (lq ^ ((lr >> 1) & 3)) * 8;
  const int aoff = (wm * 64 + lr) * 32 + fsw;
  const int boff = (wn * 64 + lr) * 32 + fsw;

  for (int kt = 0; kt < nk; ++kt) {
    if (kt + 1 < nk) {  // prefetch next k-tile into the other buffer
      const bf16* a1 = ga + (size_t)(kt + 1) * 32;
      const bf16* b1 = gb + (size_t)(kt + 1) * 32;
      bf16* la2 = la + ((kt + 1) & 1) * (128 * 32);
      bf16* lb2 = lb + ((kt + 1) & 1) * (128 * 32);
      GLL(a1, la2);
      GLL(a1 + (size_t)64 * lda, la2 + 64 * 32);
      GLL(b1, lb2);
      GLL(b1 + (size_t)64 * ldb, lb2 + 64 * 32);
    }
    const bf16* Ab = &As[kt & 1][0];
    const bf16* Bb = &Bs[kt & 1][0];
    short8 af[4], bfv[4];
#pragma unroll
    for (int i = 0; i < 4; ++i) af[i] = *(const short8*)(Ab + aoff + i * 16 * 32);
#pragma unroll
    for (int j = 0; j < 4; ++j) bfv[j] = *(const short8*)(Bb + boff + j * 16 * 32);
#pragma unroll
    for (int i = 0; i < 4; ++i)
#pragma unroll
      for (int j = 0; j < 4; ++j)
        acc[i][j] = __builtin_amdgcn_mfma_f32_16x16x32_bf16(af[i], bfv[j], acc[i][j], 0, 0, 0);
    __syncthreads();
  }

  // epilogue: C/D frag map col=lane&15, row=(lane>>4)*4+r [m89-verified]
  float* Cf = (float*)Cv;
  bf16* Cb = (bf16*)Cv;
  const size_t cb = sC * bz;
#pragma unroll
  for (int i = 0; i < 4; ++i) {
    const int row = m0 + wm * 64 + i * 16 + lq * 4;
#pragma unroll
    for (int j = 0; j < 4; ++j) {
      const int col = n0 + wn * 64 + j * 16 + lr;
      const float bb = HAS_BIAS ? bias[col] : 0.f;
#pragma unroll
      for (int r = 0; r < 4; ++r) {
        float val = acc[i][j][r] * alpha + bb;
        if (GELU) val = 0.5f * val * (1.f + erff(val * 0.70710678118654752f));
        if (HAS_RES) val += res[(size_t)(row + r) * N + col];
        const size_t idx = cb + (size_t)(row + r) * N + col;
        if (OUT_BF16) Cb[idx] = __float2bfloat16(val);
        else Cf[idx] = val;
        if (VTR) {
          if (col >= 2048) {  // V cols: also write V^T [b][col-2048][row%S]
            const int rr = row + r;
            vtr[(((size_t)(rr >> 11) << 10) + (col - 2048)) * 2048 + (rr & 2047)] =
                __float2bfloat16(val);
          }
        }
      }
    }
  }
}

extern "C" void kernel_launch(void* const* d_in, const int* in_sizes, int n_in,
                              void* d_out, int out_size, void* d_ws, size_t ws_size,
                              hipStream_t stream) {
  const int B = 4, S = 2048, D = 1024, DFF = 4096;
  const int M = B * S;
  const float* x   = (const float*)d_in[0];
  const float* wq  = (const float*)d_in[1];
  const float* bq  = (const float*)d_in[2];
  const float* wk  = (const float*)d_in[3];
  const float* bk  = (const float*)d_in[4];
  const float* wv  = (const float*)d_in[5];
  const float* bv  = (const float*)d_in[6];
  const float* wo  = (const float*)d_in[7];
  const float* bo  = (const float*)d_in[8];
  const float* w1  = (const float*)d_in[9];
  const float* b1  = (const float*)d_in[10];
  const float* w2  = (const float*)d_in[11];
  const float* b2  = (const float*)d_in[12];
  const float* g1  = (const float*)d_in[13];
  const float* be1 = (const float*)d_in[14];
  const float* g2  = (const float*)d_in[15];
  const float* be2 = (const float*)d_in[16];
  float* out = (float*)d_out;

  // workspace arena:
  //  0-6 wqkvT  6-8 woT  8-16 w1T  16-24 w2T  24 bqkv  25-41 h (bf16 MxD)
  //  41-89 qkv (bf16 Mx3072) / later hidden (bf16 MxDFF, 41-105)
  //  89-105 vT [4][D][S] bf16 (written by QKV epilogue)
  //  105+  scores fp32, chunk*16MB
  char* wsb = (char*)d_ws;
  const size_t MB1 = 1ull << 20;
  bf16* wqkvT = (bf16*)(wsb + 0 * MB1);
  bf16* woT   = (bf16*)(wsb + 6 * MB1);
  bf16* w1T   = (bf16*)(wsb + 8 * MB1);
  bf16* w2T   = (bf16*)(wsb + 16 * MB1);
  float* bqkv = (float*)(wsb + 24 * MB1);
  bf16* h     = (bf16*)(wsb + 25 * MB1);
  bf16* qkv   = (bf16*)(wsb + 41 * MB1);
  bf16* hidden = (bf16*)(wsb + 41 * MB1);
  bf16* vTall = (bf16*)(wsb + 89 * MB1);
  float* sc   = (float*)(wsb + 105 * MB1);

  int chunk = 1;
  if (ws_size > 105 * MB1) {
    size_t c = (ws_size - 105 * MB1) / (16 * MB1);
    chunk = (int)(c > 4 ? 4 : (c < 1 ? 1 : c));
  }

  dim3 tb(32, 8);
  wtrans_kernel<<<dim3(32, 32), tb, 0, stream>>>(wq, wqkvT, D, D);
  wtrans_kernel<<<dim3(32, 32), tb, 0, stream>>>(wk, wqkvT + (size_t)1024 * 1024, D, D);
  wtrans_kernel<<<dim3(32, 32), tb, 0, stream>>>(wv, wqkvT + (size_t)2048 * 1024, D, D);
  wtrans_kernel<<<dim3(32, 32), tb, 0, stream>>>(wo, woT, D, D);
  wtrans_kernel<<<dim3(128, 32), tb, 0, stream>>>(w1, w1T, D, DFF);
  wtrans_kernel<<<dim3(32, 128), tb, 0, stream>>>(w2, w2T, DFF, D);
  hipMemcpyAsync(bqkv, bq, 4096, hipMemcpyDeviceToDevice, stream);
  hipMemcpyAsync(bqkv + 1024, bk, 4096, hipMemcpyDeviceToDevice, stream);
  hipMemcpyAsync(bqkv + 2048, bv, 4096, hipMemcpyDeviceToDevice, stream);

  // h = LN1(x)
  ln_kernel<<<M, 256, 0, stream>>>(x, g1, be1, h);

  // qkv = h @ [wq|wk|wv] + biases; V cols also emitted transposed into vTall
  gemmT<true, true, false, false, true><<<24 * 64, 256, 0, stream>>>(
      h, D, 0, wqkvT, D, 0, qkv, 0, bqkv, nullptr, vTall, 3072, D, 1.f, 24, 64);

  for (int b0 = 0; b0 < B; b0 += chunk) {
    int c = (B - b0 < chunk) ? (B - b0) : chunk;
    // scores = q @ k^T * 0.125 (fp32)
    gemmT<false, false, false, false, false><<<256 * c, 256, 0, stream>>>(
        qkv + (size_t)b0 * S * 3072, 3072, (size_t)S * 3072,
        qkv + (size_t)b0 * S * 3072 + 1024, 3072, (size_t)S * 3072,
        sc, (size_t)S * S, nullptr, nullptr, nullptr, S, D, 0.125f, 16, 16);
    softmax_kernel<<<c * S, 256, 0, stream>>>(sc);
    // ctx = probs @ vT^T (probs bf16 in-place over fp32 rows, pitch 2S)
    gemmT<true, false, false, false, false><<<128 * c, 256, 0, stream>>>(
        (const bf16*)sc, 2 * S, (size_t)S * 2 * S,
        vTall + (size_t)b0 * D * S, S, (size_t)D * S,
        h + (size_t)b0 * S * D, (size_t)S * D, nullptr, nullptr, nullptr, D, S, 1.f, 8, 16);
  }

  // x2 = ctx @ wo + bo + x -> d_out (fp32)
  gemmT<false, true, true, false, false><<<8 * 64, 256, 0, stream>>>(
      h, D, 0, woT, D, 0, out, 0, bo, x, nullptr, D, D, 1.f, 8, 64);

  // h = LN2(x2)
  ln_kernel<<<M, 256, 0, stream>>>(out, g2, be2, h);

  // hidden = gelu(h @ w1 + b1)
  gemmT<true, true, false, true, false><<<32 * 64, 256, 0, stream>>>(
      h, D, 0, w1T, D, 0, hidden, 0, b1, nullptr, nullptr, DFF, D, 1.f, 32, 64);

  // out = hidden @ w2 + b2 + x2 (in-place residual)
  gemmT<false, true, true, false, false><<<8 * 64, 256, 0, stream>>>(
      hidden, DFF, 0, w2T, DFF, 0, out, 0, b2, out, nullptr, D, DFF, 1.f, 8, 64);
}

// Round 12
// 443.534 us; speedup vs baseline: 1.2548x; 1.1485x over previous
//
#include <hip/hip_runtime.h>
#include <hip/hip_bf16.h>

typedef __hip_bfloat16 bf16;
typedef __attribute__((ext_vector_type(8))) short short8;
typedef __attribute__((ext_vector_type(4))) float floatx4;
typedef __attribute__((address_space(3))) char c3;

template <int V> struct ic { static constexpr int value = V; };

__device__ __forceinline__ unsigned short f2bf(float x) {
  unsigned u = __builtin_bit_cast(unsigned, x);
  unsigned r = (u + 0x7fffu + ((u >> 16) & 1u)) >> 16;
  return (unsigned short)r;
}

#define GLL(g, l) __builtin_amdgcn_global_load_lds(                                  \
    (const __attribute__((address_space(1))) void*)(g),                              \
    (__attribute__((address_space(3))) void*)(l), 16, 0, 0)

template <int N> __device__ __forceinline__ void vmwait() {
  asm volatile("s_waitcnt vmcnt(%0)" ::"i"(N) : "memory");
}
template <int OFF> __device__ __forceinline__ short8 dsr(unsigned a) {
  short8 r;
  asm volatile("ds_read_b128 %0, %1 offset:%2" : "=v"(r) : "v"(a), "i"(OFF));
  return r;
}
__device__ __forceinline__ void lgkm0_fence() {
  asm volatile("s_waitcnt lgkmcnt(0)" ::: "memory");
  __builtin_amdgcn_sched_barrier(0);
}

// ------ merged weight prep: 6 transposes (fp32 [K][N] -> bf16 [N][K]) + biases --
// grid 12289 blocks of (32,8):
//  [0,1024) wq  [1024,2048) wk  [2048,3072) wv  [3072,4096) wo
//  [4096,8192) w1 (128x32)     [8192,12288) w2 (32x128)     12288: bias concat
__global__ __launch_bounds__(256) void wtrans_all(
    const float* __restrict__ wq, const float* __restrict__ wk,
    const float* __restrict__ wv, const float* __restrict__ wo,
    const float* __restrict__ w1, const float* __restrict__ w2,
    bf16* __restrict__ wqkvT, bf16* __restrict__ woT,
    bf16* __restrict__ w1T, bf16* __restrict__ w2T,
    const float* __restrict__ bq, const float* __restrict__ bk,
    const float* __restrict__ bv, float* __restrict__ bqkv) {
  const int id = blockIdx.x;
  if (id == 12288) {
    int t = threadIdx.y * 32 + threadIdx.x;
    for (int i = t; i < 1024; i += 256) {
      bqkv[i] = bq[i];
      bqkv[1024 + i] = bk[i];
      bqkv[2048 + i] = bv[i];
    }
    return;
  }
  const float* in;
  bf16* out;
  int K, N, bx, by;
  if (id < 4096) {
    const int seg = id >> 10, r = id & 1023;
    bx = r & 31; by = r >> 5; K = 1024; N = 1024;
    if (seg == 0) { in = wq; out = wqkvT; }
    else if (seg == 1) { in = wk; out = wqkvT + (size_t)1024 * 1024; }
    else if (seg == 2) { in = wv; out = wqkvT + (size_t)2048 * 1024; }
    else { in = wo; out = woT; }
  } else if (id < 8192) {
    const int r = id - 4096;
    bx = r & 127; by = r >> 7; K = 1024; N = 4096;
    in = w1; out = w1T;
  } else {
    const int r = id - 8192;
    bx = r & 31; by = r >> 5; K = 4096; N = 1024;
    in = w2; out = w2T;
  }
  __shared__ float tile[32][33];
  const int tx = threadIdx.x, ty = threadIdx.y;
  const int n0 = bx * 32, k0 = by * 32;
#pragma unroll
  for (int i = 0; i < 32; i += 8)
    tile[ty + i][tx] = in[(size_t)(k0 + ty + i) * N + (n0 + tx)];
  __syncthreads();
#pragma unroll
  for (int i = 0; i < 32; i += 8)
    out[(size_t)(n0 + ty + i) * K + (k0 + tx)] = __float2bfloat16(tile[tx][ty + i]);
}

// ---------------- LayerNorm fp32 -> bf16, D=1024, one block(256)/row ------------
__global__ __launch_bounds__(256) void ln_kernel(const float* __restrict__ x,
                                                 const float* __restrict__ g,
                                                 const float* __restrict__ b,
                                                 bf16* __restrict__ out) {
  const int D = 1024;
  size_t row = blockIdx.x;
  int t = threadIdx.x;
  float4 v = ((const float4*)(x + row * D))[t];
  float s  = v.x + v.y + v.z + v.w;
  float ss = v.x * v.x + v.y * v.y + v.z * v.z + v.w * v.w;
#pragma unroll
  for (int off = 32; off > 0; off >>= 1) {
    s  += __shfl_xor(s, off);
    ss += __shfl_xor(ss, off);
  }
  __shared__ float rs[4], rss[4];
  int wv = t >> 6;
  if ((t & 63) == 0) { rs[wv] = s; rss[wv] = ss; }
  __syncthreads();
  s  = rs[0] + rs[1] + rs[2] + rs[3];
  ss = rss[0] + rss[1] + rss[2] + rss[3];
  float mu  = s * (1.f / D);
  float inv = rsqrtf(ss * (1.f / D) - mu * mu + 1e-5f);
  float4 gv = ((const float4*)g)[t];
  float4 bv = ((const float4*)b)[t];
  ushort4 o;
  o.x = f2bf((v.x - mu) * inv * gv.x + bv.x);
  o.y = f2bf((v.y - mu) * inv * gv.y + bv.y);
  o.z = f2bf((v.z - mu) * inv * gv.z + bv.z);
  o.w = f2bf((v.w - mu) * inv * gv.w + bv.w);
  ((ushort4*)(out + row * D))[t] = o;
}

// ------ wave-per-row softmax: fp32 row (2048) -> bf16 in place, no barriers -----
// 4 rows per 256-thread block (one wave each); pure-shfl reductions.
__global__ __launch_bounds__(256) void softmax_wave(float* sc) {
  const int S = 2048;
  const int wave = threadIdx.x >> 6, lane = threadIdx.x & 63;
  float* p = sc + ((size_t)blockIdx.x * 4 + wave) * S;
  float f[32];
  const float4* pv = (const float4*)p;
#pragma unroll
  for (int j = 0; j < 8; ++j) {
    float4 v = pv[lane + 64 * j];
    f[4 * j] = v.x; f[4 * j + 1] = v.y; f[4 * j + 2] = v.z; f[4 * j + 3] = v.w;
  }
  float m = f[0];
#pragma unroll
  for (int j = 1; j < 32; ++j) m = fmaxf(m, f[j]);
#pragma unroll
  for (int off = 32; off > 0; off >>= 1) m = fmaxf(m, __shfl_xor(m, off));
  float s = 0.f;
#pragma unroll
  for (int j = 0; j < 32; ++j) { f[j] = __expf(f[j] - m); s += f[j]; }
#pragma unroll
  for (int off = 32; off > 0; off >>= 1) s += __shfl_xor(s, off);
  const float inv = 1.f / s;
  uint2* po = (uint2*)p;  // bf16 row occupies first half of the fp32 row
#pragma unroll
  for (int j = 0; j < 8; ++j) {
    unsigned lo = (unsigned)f2bf(f[4 * j] * inv) | ((unsigned)f2bf(f[4 * j + 1] * inv) << 16);
    unsigned hi = (unsigned)f2bf(f[4 * j + 2] * inv) | ((unsigned)f2bf(f[4 * j + 3] * inv) << 16);
    po[lane + 64 * j] = make_uint2(lo, hi);
  }
}

// ---------------- deep-prefetch quadrant GEMM (r7 best-known, verbatim) ---------
// BM=256, BN=NF*64, BK=64; 8 waves (2Mx4N). P0 (m0n0, Bs0 frags kept), P1 (m0n1),
// P23 (m1n1 + m1n0). Per-half slot re-staged with t+2 right after its last
// reader's barrier; FIFO-counted vmcnt, never 0 in steady state; peeled tails.
template <int NF, bool OUT_BF16, bool HAS_BIAS, bool HAS_RES, bool GELU, bool VTR>
__global__ __launch_bounds__(512, 2) void gemm7(
    const bf16* __restrict__ A, int lda, size_t sA,
    const bf16* __restrict__ BT, int ldb, size_t sB,
    void* Cv, size_t sC,
    const float* __restrict__ bias, const float* res, bf16* vtr,
    int N, int K, float alpha, int gx, int gy) {
  constexpr int BN = NF * 64;
  constexpr int NI = NF / 2;
  constexpr int BHALF = NF == 4 ? 16384 : 8192;
  __shared__ __align__(16) char lds_storage[65536 + (NF == 4 ? 65536 : 32768)];
  const unsigned ldsAu = (unsigned)(uintptr_t)(c3*)lds_storage;
  const unsigned ldsBu = ldsAu + 65536;

  const int tid = threadIdx.x;
  const int lane = tid & 63;
  const int wave = tid >> 6;
  const int wm = wave >> 2, wn = wave & 3;
  const int lr = lane & 15, lq = lane >> 4;

  int id = blockIdx.x;
  const int nwg = gridDim.x;
  if ((nwg & 7) == 0) id = (id & 7) * (nwg >> 3) + (id >> 3);  // XCD swizzle
  const int bx = id % gx;
  const int rem = id / gx;
  const int by = rem % gy;
  const int bz = rem / gy;
  const int m0 = by * 256, n0 = bx * BN;

  const int srow = tid >> 3;
  const int schunk = ((tid & 7) ^ (srow & 7)) * 8;
  const bf16* gA = A + sA * bz + (size_t)(m0 + srow) * lda + schunk;
  const bf16* gB = BT + sB * bz + (size_t)(n0 + srow) * ldb + schunk;

  const int nk = K >> 6;

  auto stA = [&](int tt, int h) {
    const bf16* s = gA + (size_t)(h * 128) * lda + (size_t)tt * 64;
    char* d = lds_storage + (((tt & 1) * 2 + h) << 14) + tid * 16;
    GLL(s, d);
    GLL(s + (size_t)64 * lda, d + 8192);
  };
  auto stB = [&](int tt, int h) {
    const bf16* s = gB + (size_t)(h * (BN / 2)) * ldb + (size_t)tt * 64;
    char* d = lds_storage + 65536 + ((tt & 1) * 2 + h) * BHALF + tid * 16;
    GLL(s, d);
    if constexpr (NF == 4) GLL(s + (size_t)64 * ldb, d + 8192);
  };

  const unsigned aB0 = (wm * 64 + lr) * 128 + ((lq ^ (lr & 7)) << 4);
  const unsigned bRow = (NF == 4) ? (wn * 32 + lr) : (wn * 16 + lr);
  const unsigned bB0 = bRow * 128 + ((lq ^ (lr & 7)) << 4);

  floatx4 acc[2][2][4][NI] = {};

  // prologue: A0(0),B0(0),B1(0),A1(0),A0(1),B0(1),B1(1); retire A0(0),B0(0)
  stA(0, 0); stB(0, 0); stB(0, 1); stA(0, 1);
  stA(1, 0); stB(1, 0); stB(1, 1);
  vmwait<NF == 4 ? 10 : 7>();
  __builtin_amdgcn_s_barrier();

  auto tile_body = [&](int t, auto modeC) {
    constexpr int MODE = decltype(modeC)::value;  // 0 steady, 1 nk-2, 2 nk-1
    constexpr int W0  = MODE < 2 ? (NF == 4 ? 10 : 8) : 2;
    constexpr int W1  = MODE == 0 ? (NF == 4 ? 12 : 9)
                                  : (MODE == 1 ? (NF == 4 ? 8 : 6) : 0);
    constexpr int W23 = MODE == 0 ? (NF == 4 ? 10 : 7)
                                  : (MODE == 1 ? (NF == 4 ? 4 : 3) : -1);
    const unsigned As0 = ldsAu + (((t & 1) * 2 + 0) << 14);
    const unsigned As1 = As0 + 16384;
    const unsigned Bs0 = ldsBu + ((t & 1) * 2 + 0) * BHALF;
    const unsigned Bs1 = Bs0 + BHALF;
    short8 a0[4], a1[4], b0[NI], b1[NI], bb0[NI], bb1[NI];

    // ===== P0: (m0,n0); keep Bs0 frags (bb); stage A1(t+1)
    {
      const unsigned aA = As0 + aB0, aX = aA ^ 64;
      a0[0] = dsr<0>(aA);  a0[1] = dsr<2048>(aA);  a0[2] = dsr<4096>(aA);  a0[3] = dsr<6144>(aA);
      a1[0] = dsr<0>(aX);  a1[1] = dsr<2048>(aX);  a1[2] = dsr<4096>(aX);  a1[3] = dsr<6144>(aX);
      const unsigned bA = Bs0 + bB0, bX = bA ^ 64;
      bb0[0] = dsr<0>(bA); bb1[0] = dsr<0>(bX);
      if constexpr (NI > 1) { bb0[1] = dsr<2048>(bA); bb1[1] = dsr<2048>(bX); }
    }
    if constexpr (MODE < 2) stA(t + 1, 1);
    lgkm0_fence();
    __builtin_amdgcn_s_setprio(1);
#pragma unroll
    for (int mi = 0; mi < 4; ++mi)
#pragma unroll
      for (int ni = 0; ni < NI; ++ni)
        acc[0][0][mi][ni] = __builtin_amdgcn_mfma_f32_16x16x32_bf16(a0[mi], bb0[ni], acc[0][0][mi][ni], 0, 0, 0);
#pragma unroll
    for (int mi = 0; mi < 4; ++mi)
#pragma unroll
      for (int ni = 0; ni < NI; ++ni)
        acc[0][0][mi][ni] = __builtin_amdgcn_mfma_f32_16x16x32_bf16(a1[mi], bb1[ni], acc[0][0][mi][ni], 0, 0, 0);
    __builtin_amdgcn_s_setprio(0);
    vmwait<W0>();
    __builtin_amdgcn_s_barrier();

    // ===== P1: (m0,n1); reads Bs1; stage A0(t+2), B0(t+2)
    short8 b0l[NI], b1l[NI];
    {
      const unsigned bA = Bs1 + bB0, bX = bA ^ 64;
      b0l[0] = dsr<0>(bA); b1l[0] = dsr<0>(bX);
      if constexpr (NI > 1) { b0l[1] = dsr<2048>(bA); b1l[1] = dsr<2048>(bX); }
    }
    if constexpr (MODE == 0) { stA(t + 2, 0); stB(t + 2, 0); }
    lgkm0_fence();
    __builtin_amdgcn_s_setprio(1);
#pragma unroll
    for (int mi = 0; mi < 4; ++mi)
#pragma unroll
      for (int ni = 0; ni < NI; ++ni)
        acc[0][1][mi][ni] = __builtin_amdgcn_mfma_f32_16x16x32_bf16(a0[mi], b0l[ni], acc[0][1][mi][ni], 0, 0, 0);
#pragma unroll
    for (int mi = 0; mi < 4; ++mi)
#pragma unroll
      for (int ni = 0; ni < NI; ++ni)
        acc[0][1][mi][ni] = __builtin_amdgcn_mfma_f32_16x16x32_bf16(a1[mi], b1l[ni], acc[0][1][mi][ni], 0, 0, 0);
    __builtin_amdgcn_s_setprio(0);
    vmwait<W1>();
    __builtin_amdgcn_s_barrier();

    // ===== P23: (m1,n1) with b (Bs1 regs), then (m1,n0) with bb (kept Bs0 regs);
    //            reads As1; stage B1(t+2)
    {
      const unsigned aA = As1 + aB0, aX = aA ^ 64;
      a0[0] = dsr<0>(aA);  a0[1] = dsr<2048>(aA);  a0[2] = dsr<4096>(aA);  a0[3] = dsr<6144>(aA);
      a1[0] = dsr<0>(aX);  a1[1] = dsr<2048>(aX);  a1[2] = dsr<4096>(aX);  a1[3] = dsr<6144>(aX);
    }
    if constexpr (MODE == 0) stB(t + 2, 1);
    lgkm0_fence();
    __builtin_amdgcn_s_setprio(1);
#pragma unroll
    for (int mi = 0; mi < 4; ++mi)
#pragma unroll
      for (int ni = 0; ni < NI; ++ni)
        acc[1][1][mi][ni] = __builtin_amdgcn_mfma_f32_16x16x32_bf16(a0[mi], b0l[ni], acc[1][1][mi][ni], 0, 0, 0);
#pragma unroll
    for (int mi = 0; mi < 4; ++mi)
#pragma unroll
      for (int ni = 0; ni < NI; ++ni)
        acc[1][1][mi][ni] = __builtin_amdgcn_mfma_f32_16x16x32_bf16(a1[mi], b1l[ni], acc[1][1][mi][ni], 0, 0, 0);
#pragma unroll
    for (int mi = 0; mi < 4; ++mi)
#pragma unroll
      for (int ni = 0; ni < NI; ++ni)
        acc[1][0][mi][ni] = __builtin_amdgcn_mfma_f32_16x16x32_bf16(a0[mi], bb0[ni], acc[1][0][mi][ni], 0, 0, 0);
#pragma unroll
    for (int mi = 0; mi < 4; ++mi)
#pragma unroll
      for (int ni = 0; ni < NI; ++ni)
        acc[1][0][mi][ni] = __builtin_amdgcn_mfma_f32_16x16x32_bf16(a1[mi], bb1[ni], acc[1][0][mi][ni], 0, 0, 0);
    __builtin_amdgcn_s_setprio(0);
    if constexpr (W23 >= 0) {
      vmwait<W23>();
      __builtin_amdgcn_s_barrier();
    }
  };

  for (int t = 0; t + 2 < nk; ++t) tile_body(t, ic<0>{});
  tile_body(nk - 2, ic<1>{});
  tile_body(nk - 1, ic<2>{});

  // epilogue: C/D frag map col=lane&15, row=(lane>>4)*4+r [m89-verified]
  float* Cf = (float*)Cv;
  bf16* Cb = (bf16*)Cv;
  const size_t cb = sC * bz;
#pragma unroll
  for (int mq = 0; mq < 2; ++mq)
#pragma unroll
    for (int nq = 0; nq < 2; ++nq)
#pragma unroll
      for (int mi = 0; mi < 4; ++mi) {
        const int row = m0 + mq * 128 + wm * 64 + mi * 16 + lq * 4;
#pragma unroll
        for (int ni = 0; ni < NI; ++ni) {
          const int col = n0 + nq * (BN / 2) + wn * (BN / 8) + ni * 16 + lr;
          const float bb = HAS_BIAS ? bias[col] : 0.f;
#pragma unroll
          for (int r = 0; r < 4; ++r) {
            float val = acc[mq][nq][mi][ni][r] * alpha + bb;
            if (GELU) val = 0.5f * val * (1.f + erff(val * 0.70710678118654752f));
            if (HAS_RES) val += res[(size_t)(row + r) * N + col];
            const size_t idx = cb + (size_t)(row + r) * N + col;
            if (OUT_BF16) Cb[idx] = __float2bfloat16(val);
            else Cf[idx] = val;
            if (VTR) {
              if (col >= 2048) {  // V cols: also write V^T [b][col-2048][row%S]
                const int rr = row + r;
                vtr[(((size_t)(rr >> 11) << 10) + (col - 2048)) * 2048 + (rr & 2047)] =
                    __float2bfloat16(val);
              }
            }
          }
        }
      }
}

extern "C" void kernel_launch(void* const* d_in, const int* in_sizes, int n_in,
                              void* d_out, int out_size, void* d_ws, size_t ws_size,
                              hipStream_t stream) {
  const int B = 4, S = 2048, D = 1024, DFF = 4096;
  const int M = B * S;
  const float* x   = (const float*)d_in[0];
  const float* wq  = (const float*)d_in[1];
  const float* bq  = (const float*)d_in[2];
  const float* wk  = (const float*)d_in[3];
  const float* bk  = (const float*)d_in[4];
  const float* wv  = (const float*)d_in[5];
  const float* bv  = (const float*)d_in[6];
  const float* wo  = (const float*)d_in[7];
  const float* bo  = (const float*)d_in[8];
  const float* w1  = (const float*)d_in[9];
  const float* b1  = (const float*)d_in[10];
  const float* w2  = (const float*)d_in[11];
  const float* b2  = (const float*)d_in[12];
  const float* g1  = (const float*)d_in[13];
  const float* be1 = (const float*)d_in[14];
  const float* g2  = (const float*)d_in[15];
  const float* be2 = (const float*)d_in[16];
  float* out = (float*)d_out;

  // workspace arena:
  //  0-6 wqkvT  6-8 woT  8-16 w1T  16-24 w2T  24 bqkv  25-41 h (bf16 MxD)
  //  41-89 qkv (bf16 Mx3072) / later hidden (bf16 MxDFF, 41-105)
  //  89-105 vT [4][D][S] bf16 (written by QKV epilogue)
  //  105+  scores fp32, chunk*16MB
  char* wsb = (char*)d_ws;
  const size_t MB1 = 1ull << 20;
  bf16* wqkvT = (bf16*)(wsb + 0 * MB1);
  bf16* woT   = (bf16*)(wsb + 6 * MB1);
  bf16* w1T   = (bf16*)(wsb + 8 * MB1);
  bf16* w2T   = (bf16*)(wsb + 16 * MB1);
  float* bqkv = (float*)(wsb + 24 * MB1);
  bf16* h     = (bf16*)(wsb + 25 * MB1);
  bf16* qkv   = (bf16*)(wsb + 41 * MB1);
  bf16* hidden = (bf16*)(wsb + 41 * MB1);
  bf16* vTall = (bf16*)(wsb + 89 * MB1);
  float* sc   = (float*)(wsb + 105 * MB1);

  int chunk = 1;
  if (ws_size > 105 * MB1) {
    size_t c = (ws_size - 105 * MB1) / (16 * MB1);
    chunk = (int)(c > 4 ? 4 : (c < 1 ? 1 : c));
  }

  // merged weight transpose + bias concat (one dispatch)
  wtrans_all<<<12289, dim3(32, 8), 0, stream>>>(
      wq, wk, wv, wo, w1, w2, wqkvT, woT, w1T, w2T, bq, bk, bv, bqkv);

  // h = LN1(x)
  ln_kernel<<<M, 256, 0, stream>>>(x, g1, be1, h);

  // qkv = h @ [wq|wk|wv] + biases; V cols also emitted transposed into vTall
  gemm7<2, true, true, false, false, true><<<24 * 32, 512, 0, stream>>>(
      h, D, 0, wqkvT, D, 0, qkv, 0, bqkv, nullptr, vTall, 3072, D, 1.f, 24, 32);

  for (int b0 = 0; b0 < B; b0 += chunk) {
    int c = (B - b0 < chunk) ? (B - b0) : chunk;
    // scores = q @ k^T * 0.125 (fp32)
    gemm7<4, false, false, false, false, false><<<64 * c, 512, 0, stream>>>(
        qkv + (size_t)b0 * S * 3072, 3072, (size_t)S * 3072,
        qkv + (size_t)b0 * S * 3072 + 1024, 3072, (size_t)S * 3072,
        sc, (size_t)S * S, nullptr, nullptr, nullptr, S, D, 0.125f, 8, 8);
    softmax_wave<<<c * S / 4, 256, 0, stream>>>(sc);
    // ctx = probs @ vT^T (probs bf16 in-place over fp32 rows, pitch 2S)
    gemm7<2, true, false, false, false, false><<<64 * c, 512, 0, stream>>>(
        (const bf16*)sc, 2 * S, (size_t)S * 2 * S,
        vTall + (size_t)b0 * D * S, S, (size_t)D * S,
        h + (size_t)b0 * S * D, (size_t)S * D, nullptr, nullptr, nullptr, D, S, 1.f, 8, 8);
  }

  // x2 = ctx @ wo + bo + x -> d_out (fp32)
  gemm7<2, false, true, true, false, false><<<8 * 32, 512, 0, stream>>>(
      h, D, 0, woT, D, 0, out, 0, bo, x, nullptr, D, D, 1.f, 8, 32);

  // h = LN2(x2)
  ln_kernel<<<M, 256, 0, stream>>>(out, g2, be2, h);

  // hidden = gelu(h @ w1 + b1)
  gemm7<4, true, true, false, true, false><<<16 * 32, 512, 0, stream>>>(
      h, D, 0, w1T, D, 0, hidden, 0, b1, nullptr, nullptr, DFF, D, 1.f, 16, 32);

  // out = hidden @ w2 + b2 + x2 (in-place residual)
  gemm7<2, false, true, true, false, false><<<8 * 32, 512, 0, stream>>>(
      hidden, DFF, 0, w2T, DFF, 0, out, 0, b2, out, nullptr, D, DFF, 1.f, 8, 32);
}

// Round 13
// 437.099 us; speedup vs baseline: 1.2733x; 1.0147x over previous
//
#include <hip/hip_runtime.h>
#include <hip/hip_bf16.h>

typedef __hip_bfloat16 bf16;
typedef __attribute__((ext_vector_type(8))) short short8;
typedef __attribute__((ext_vector_type(4))) float floatx4;
typedef __attribute__((address_space(3))) char c3;

template <int V> struct ic { static constexpr int value = V; };

__device__ __forceinline__ unsigned short f2bf(float x) {
  unsigned u = __builtin_bit_cast(unsigned, x);
  unsigned r = (u + 0x7fffu + ((u >> 16) & 1u)) >> 16;
  return (unsigned short)r;
}

#define GLL(g, l) __builtin_amdgcn_global_load_lds(                                  \
    (const __attribute__((address_space(1))) void*)(g),                              \
    (__attribute__((address_space(3))) void*)(l), 16, 0, 0)

template <int N> __device__ __forceinline__ void vmwait() {
  asm volatile("s_waitcnt vmcnt(%0)" ::"i"(N) : "memory");
}
template <int OFF> __device__ __forceinline__ short8 dsr(unsigned a) {
  short8 r;
  asm volatile("ds_read_b128 %0, %1 offset:%2" : "=v"(r) : "v"(a), "i"(OFF));
  return r;
}
__device__ __forceinline__ void lgkm0_fence() {
  asm volatile("s_waitcnt lgkmcnt(0)" ::: "memory");
  __builtin_amdgcn_sched_barrier(0);
}

// ---- wave-per-row LayerNorm body: 1024 fp32 -> 1024 bf16, one 64-lane wave ----
__device__ __forceinline__ void ln_row_wave(const float* __restrict__ xr,
                                            const float* __restrict__ g,
                                            const float* __restrict__ b,
                                            bf16* __restrict__ outr, int lane) {
  const float4* xv = (const float4*)xr;
  float4 v[4];
  float s = 0.f, ss = 0.f;
#pragma unroll
  for (int j = 0; j < 4; ++j) {
    v[j] = xv[lane + 64 * j];
    s  += v[j].x + v[j].y + v[j].z + v[j].w;
    ss += v[j].x * v[j].x + v[j].y * v[j].y + v[j].z * v[j].z + v[j].w * v[j].w;
  }
#pragma unroll
  for (int off = 32; off > 0; off >>= 1) {
    s  += __shfl_xor(s, off);
    ss += __shfl_xor(ss, off);
  }
  const float mu  = s * (1.f / 1024.f);
  const float inv = rsqrtf(ss * (1.f / 1024.f) - mu * mu + 1e-5f);
  ushort4* ov = (ushort4*)outr;
#pragma unroll
  for (int j = 0; j < 4; ++j) {
    float4 gv = ((const float4*)g)[lane + 64 * j];
    float4 bv = ((const float4*)b)[lane + 64 * j];
    ushort4 o;
    o.x = f2bf((v[j].x - mu) * inv * gv.x + bv.x);
    o.y = f2bf((v[j].y - mu) * inv * gv.y + bv.y);
    o.z = f2bf((v[j].z - mu) * inv * gv.z + bv.z);
    o.w = f2bf((v[j].w - mu) * inv * gv.w + bv.w);
    ov[lane + 64 * j] = o;
  }
}

// ------ merged prep: 6 weight transposes + bias concat + LN1 (one dispatch) -----
// grid 14337 x 256 threads:
//  [0,1024) wq  [1024,2048) wk  [2048,3072) wv  [3072,4096) wo
//  [4096,8192) w1 (128x32)  [8192,12288) w2 (32x128)  12288: bias concat
//  [12289,14337): LN1 — rows (id-12289)*4 + wave  (wave-per-row, no barriers)
__global__ __launch_bounds__(256) void prep_kernel(
    const float* __restrict__ wq, const float* __restrict__ wk,
    const float* __restrict__ wv, const float* __restrict__ wo,
    const float* __restrict__ w1, const float* __restrict__ w2,
    bf16* __restrict__ wqkvT, bf16* __restrict__ woT,
    bf16* __restrict__ w1T, bf16* __restrict__ w2T,
    const float* __restrict__ bq, const float* __restrict__ bk,
    const float* __restrict__ bv, float* __restrict__ bqkv,
    const float* __restrict__ x, const float* __restrict__ g1,
    const float* __restrict__ be1, bf16* __restrict__ h) {
  const int id = blockIdx.x;
  const int t = threadIdx.x;
  if (id >= 12289) {  // LN1
    const size_t row = (size_t)(id - 12289) * 4 + (t >> 6);
    ln_row_wave(x + row * 1024, g1, be1, h + row * 1024, t & 63);
    return;
  }
  if (id == 12288) {  // bias concat
    for (int i = t; i < 1024; i += 256) {
      bqkv[i] = bq[i];
      bqkv[1024 + i] = bk[i];
      bqkv[2048 + i] = bv[i];
    }
    return;
  }
  const float* in;
  bf16* out;
  int K, N, bx, by;
  if (id < 4096) {
    const int seg = id >> 10, r = id & 1023;
    bx = r & 31; by = r >> 5; K = 1024; N = 1024;
    if (seg == 0) { in = wq; out = wqkvT; }
    else if (seg == 1) { in = wk; out = wqkvT + (size_t)1024 * 1024; }
    else if (seg == 2) { in = wv; out = wqkvT + (size_t)2048 * 1024; }
    else { in = wo; out = woT; }
  } else if (id < 8192) {
    const int r = id - 4096;
    bx = r & 127; by = r >> 7; K = 1024; N = 4096;
    in = w1; out = w1T;
  } else {
    const int r = id - 8192;
    bx = r & 31; by = r >> 5; K = 4096; N = 1024;
    in = w2; out = w2T;
  }
  __shared__ float tile[32][33];
  const int tx = t & 31, ty = t >> 5;
  const int n0 = bx * 32, k0 = by * 32;
#pragma unroll
  for (int i = 0; i < 32; i += 8)
    tile[ty + i][tx] = in[(size_t)(k0 + ty + i) * N + (n0 + tx)];
  __syncthreads();
#pragma unroll
  for (int i = 0; i < 32; i += 8)
    out[(size_t)(n0 + ty + i) * K + (k0 + tx)] = __float2bfloat16(tile[tx][ty + i]);
}

// ---------------- wave-per-row LN2 dispatch: 4 rows/block --------------------
__global__ __launch_bounds__(256) void ln_wave(const float* __restrict__ x,
                                               const float* __restrict__ g,
                                               const float* __restrict__ b,
                                               bf16* __restrict__ out) {
  const size_t row = (size_t)blockIdx.x * 4 + (threadIdx.x >> 6);
  ln_row_wave(x + row * 1024, g, b, out + row * 1024, threadIdx.x & 63);
}

// ------ wave-per-row softmax: fp32 row (2048) -> bf16 in place, no barriers -----
__global__ __launch_bounds__(256) void softmax_wave(float* sc) {
  const int S = 2048;
  const int wave = threadIdx.x >> 6, lane = threadIdx.x & 63;
  float* p = sc + ((size_t)blockIdx.x * 4 + wave) * S;
  float f[32];
  const float4* pv = (const float4*)p;
#pragma unroll
  for (int j = 0; j < 8; ++j) {
    float4 v = pv[lane + 64 * j];
    f[4 * j] = v.x; f[4 * j + 1] = v.y; f[4 * j + 2] = v.z; f[4 * j + 3] = v.w;
  }
  float m = f[0];
#pragma unroll
  for (int j = 1; j < 32; ++j) m = fmaxf(m, f[j]);
#pragma unroll
  for (int off = 32; off > 0; off >>= 1) m = fmaxf(m, __shfl_xor(m, off));
  float s = 0.f;
#pragma unroll
  for (int j = 0; j < 32; ++j) { f[j] = __expf(f[j] - m); s += f[j]; }
#pragma unroll
  for (int off = 32; off > 0; off >>= 1) s += __shfl_xor(s, off);
  const float inv = 1.f / s;
  uint2* po = (uint2*)p;  // bf16 row occupies first half of the fp32 row
#pragma unroll
  for (int j = 0; j < 8; ++j) {
    unsigned lo = (unsigned)f2bf(f[4 * j] * inv) | ((unsigned)f2bf(f[4 * j + 1] * inv) << 16);
    unsigned hi = (unsigned)f2bf(f[4 * j + 2] * inv) | ((unsigned)f2bf(f[4 * j + 3] * inv) << 16);
    po[lane + 64 * j] = make_uint2(lo, hi);
  }
}

// ---------------- deep-prefetch quadrant GEMM (r7/r12 best-known, verbatim) -----
// BM=256, BN=NF*64, BK=64; 8 waves (2Mx4N). P0 (m0n0, Bs0 frags kept), P1 (m0n1),
// P23 (m1n1 + m1n0). Per-half slot re-staged with t+2 right after its last
// reader's barrier; FIFO-counted vmcnt, never 0 in steady state; peeled tails.
template <int NF, bool OUT_BF16, bool HAS_BIAS, bool HAS_RES, bool GELU, bool VTR>
__global__ __launch_bounds__(512, 2) void gemm7(
    const bf16* __restrict__ A, int lda, size_t sA,
    const bf16* __restrict__ BT, int ldb, size_t sB,
    void* Cv, size_t sC,
    const float* __restrict__ bias, const float* res, bf16* vtr,
    int N, int K, float alpha, int gx, int gy) {
  constexpr int BN = NF * 64;
  constexpr int NI = NF / 2;
  constexpr int BHALF = NF == 4 ? 16384 : 8192;
  __shared__ __align__(16) char lds_storage[65536 + (NF == 4 ? 65536 : 32768)];
  const unsigned ldsAu = (unsigned)(uintptr_t)(c3*)lds_storage;
  const unsigned ldsBu = ldsAu + 65536;

  const int tid = threadIdx.x;
  const int lane = tid & 63;
  const int wave = tid >> 6;
  const int wm = wave >> 2, wn = wave & 3;
  const int lr = lane & 15, lq = lane >> 4;

  int id = blockIdx.x;
  const int nwg = gridDim.x;
  if ((nwg & 7) == 0) id = (id & 7) * (nwg >> 3) + (id >> 3);  // XCD swizzle
  const int bx = id % gx;
  const int rem = id / gx;
  const int by = rem % gy;
  const int bz = rem / gy;
  const int m0 = by * 256, n0 = bx * BN;

  const int srow = tid >> 3;
  const int schunk = ((tid & 7) ^ (srow & 7)) * 8;
  const bf16* gA = A + sA * bz + (size_t)(m0 + srow) * lda + schunk;
  const bf16* gB = BT + sB * bz + (size_t)(n0 + srow) * ldb + schunk;

  const int nk = K >> 6;

  auto stA = [&](int tt, int h) {
    const bf16* s = gA + (size_t)(h * 128) * lda + (size_t)tt * 64;
    char* d = lds_storage + (((tt & 1) * 2 + h) << 14) + tid * 16;
    GLL(s, d);
    GLL(s + (size_t)64 * lda, d + 8192);
  };
  auto stB = [&](int tt, int h) {
    const bf16* s = gB + (size_t)(h * (BN / 2)) * ldb + (size_t)tt * 64;
    char* d = lds_storage + 65536 + ((tt & 1) * 2 + h) * BHALF + tid * 16;
    GLL(s, d);
    if constexpr (NF == 4) GLL(s + (size_t)64 * ldb, d + 8192);
  };

  const unsigned aB0 = (wm * 64 + lr) * 128 + ((lq ^ (lr & 7)) << 4);
  const unsigned bRow = (NF == 4) ? (wn * 32 + lr) : (wn * 16 + lr);
  const unsigned bB0 = bRow * 128 + ((lq ^ (lr & 7)) << 4);

  floatx4 acc[2][2][4][NI] = {};

  // prologue: A0(0),B0(0),B1(0),A1(0),A0(1),B0(1),B1(1); retire A0(0),B0(0)
  stA(0, 0); stB(0, 0); stB(0, 1); stA(0, 1);
  stA(1, 0); stB(1, 0); stB(1, 1);
  vmwait<NF == 4 ? 10 : 7>();
  __builtin_amdgcn_s_barrier();

  auto tile_body = [&](int t, auto modeC) {
    constexpr int MODE = decltype(modeC)::value;  // 0 steady, 1 nk-2, 2 nk-1
    constexpr int W0  = MODE < 2 ? (NF == 4 ? 10 : 8) : 2;
    constexpr int W1  = MODE == 0 ? (NF == 4 ? 12 : 9)
                                  : (MODE == 1 ? (NF == 4 ? 8 : 6) : 0);
    constexpr int W23 = MODE == 0 ? (NF == 4 ? 10 : 7)
                                  : (MODE == 1 ? (NF == 4 ? 4 : 3) : -1);
    const unsigned As0 = ldsAu + (((t & 1) * 2 + 0) << 14);
    const unsigned As1 = As0 + 16384;
    const unsigned Bs0 = ldsBu + ((t & 1) * 2 + 0) * BHALF;
    const unsigned Bs1 = Bs0 + BHALF;
    short8 a0[4], a1[4], bb0[NI], bb1[NI];

    // ===== P0: (m0,n0); keep Bs0 frags (bb); stage A1(t+1)
    {
      const unsigned aA = As0 + aB0, aX = aA ^ 64;
      a0[0] = dsr<0>(aA);  a0[1] = dsr<2048>(aA);  a0[2] = dsr<4096>(aA);  a0[3] = dsr<6144>(aA);
      a1[0] = dsr<0>(aX);  a1[1] = dsr<2048>(aX);  a1[2] = dsr<4096>(aX);  a1[3] = dsr<6144>(aX);
      const unsigned bA = Bs0 + bB0, bX = bA ^ 64;
      bb0[0] = dsr<0>(bA); bb1[0] = dsr<0>(bX);
      if constexpr (NI > 1) { bb0[1] = dsr<2048>(bA); bb1[1] = dsr<2048>(bX); }
    }
    if constexpr (MODE < 2) stA(t + 1, 1);
    lgkm0_fence();
    __builtin_amdgcn_s_setprio(1);
#pragma unroll
    for (int mi = 0; mi < 4; ++mi)
#pragma unroll
      for (int ni = 0; ni < NI; ++ni)
        acc[0][0][mi][ni] = __builtin_amdgcn_mfma_f32_16x16x32_bf16(a0[mi], bb0[ni], acc[0][0][mi][ni], 0, 0, 0);
#pragma unroll
    for (int mi = 0; mi < 4; ++mi)
#pragma unroll
      for (int ni = 0; ni < NI; ++ni)
        acc[0][0][mi][ni] = __builtin_amdgcn_mfma_f32_16x16x32_bf16(a1[mi], bb1[ni], acc[0][0][mi][ni], 0, 0, 0);
    __builtin_amdgcn_s_setprio(0);
    vmwait<W0>();
    __builtin_amdgcn_s_barrier();

    // ===== P1: (m0,n1); reads Bs1; stage A0(t+2), B0(t+2)
    short8 b0l[NI], b1l[NI];
    {
      const unsigned bA = Bs1 + bB0, bX = bA ^ 64;
      b0l[0] = dsr<0>(bA); b1l[0] = dsr<0>(bX);
      if constexpr (NI > 1) { b0l[1] = dsr<2048>(bA); b1l[1] = dsr<2048>(bX); }
    }
    if constexpr (MODE == 0) { stA(t + 2, 0); stB(t + 2, 0); }
    lgkm0_fence();
    __builtin_amdgcn_s_setprio(1);
#pragma unroll
    for (int mi = 0; mi < 4; ++mi)
#pragma unroll
      for (int ni = 0; ni < NI; ++ni)
        acc[0][1][mi][ni] = __builtin_amdgcn_mfma_f32_16x16x32_bf16(a0[mi], b0l[ni], acc[0][1][mi][ni], 0, 0, 0);
#pragma unroll
    for (int mi = 0; mi < 4; ++mi)
#pragma unroll
      for (int ni = 0; ni < NI; ++ni)
        acc[0][1][mi][ni] = __builtin_amdgcn_mfma_f32_16x16x32_bf16(a1[mi], b1l[ni], acc[0][1][mi][ni], 0, 0, 0);
    __builtin_amdgcn_s_setprio(0);
    vmwait<W1>();
    __builtin_amdgcn_s_barrier();

    // ===== P23: (m1,n1) with b0l/b1l, then (m1,n0) with kept bb; reads As1;
    //            stage B1(t+2)
    {
      const unsigned aA = As1 + aB0, aX = aA ^ 64;
      a0[0] = dsr<0>(aA);  a0[1] = dsr<2048>(aA);  a0[2] = dsr<4096>(aA);  a0[3] = dsr<6144>(aA);
      a1[0] = dsr<0>(aX);  a1[1] = dsr<2048>(aX);  a1[2] = dsr<4096>(aX);  a1[3] = dsr<6144>(aX);
    }
    if constexpr (MODE == 0) stB(t + 2, 1);
    lgkm0_fence();
    __builtin_amdgcn_s_setprio(1);
#pragma unroll
    for (int mi = 0; mi < 4; ++mi)
#pragma unroll
      for (int ni = 0; ni < NI; ++ni)
        acc[1][1][mi][ni] = __builtin_amdgcn_mfma_f32_16x16x32_bf16(a0[mi], b0l[ni], acc[1][1][mi][ni], 0, 0, 0);
#pragma unroll
    for (int mi = 0; mi < 4; ++mi)
#pragma unroll
      for (int ni = 0; ni < NI; ++ni)
        acc[1][1][mi][ni] = __builtin_amdgcn_mfma_f32_16x16x32_bf16(a1[mi], b1l[ni], acc[1][1][mi][ni], 0, 0, 0);
#pragma unroll
    for (int mi = 0; mi < 4; ++mi)
#pragma unroll
      for (int ni = 0; ni < NI; ++ni)
        acc[1][0][mi][ni] = __builtin_amdgcn_mfma_f32_16x16x32_bf16(a0[mi], bb0[ni], acc[1][0][mi][ni], 0, 0, 0);
#pragma unroll
    for (int mi = 0; mi < 4; ++mi)
#pragma unroll
      for (int ni = 0; ni < NI; ++ni)
        acc[1][0][mi][ni] = __builtin_amdgcn_mfma_f32_16x16x32_bf16(a1[mi], bb1[ni], acc[1][0][mi][ni], 0, 0, 0);
    __builtin_amdgcn_s_setprio(0);
    if constexpr (W23 >= 0) {
      vmwait<W23>();
      __builtin_amdgcn_s_barrier();
    }
  };

  for (int t = 0; t + 2 < nk; ++t) tile_body(t, ic<0>{});
  tile_body(nk - 2, ic<1>{});
  tile_body(nk - 1, ic<2>{});

  // epilogue: C/D frag map col=lane&15, row=(lane>>4)*4+r [m89-verified]
  float* Cf = (float*)Cv;
  bf16* Cb = (bf16*)Cv;
  const size_t cb = sC * bz;
#pragma unroll
  for (int mq = 0; mq < 2; ++mq)
#pragma unroll
    for (int nq = 0; nq < 2; ++nq)
#pragma unroll
      for (int mi = 0; mi < 4; ++mi) {
        const int row = m0 + mq * 128 + wm * 64 + mi * 16 + lq * 4;
#pragma unroll
        for (int ni = 0; ni < NI; ++ni) {
          const int col = n0 + nq * (BN / 2) + wn * (BN / 8) + ni * 16 + lr;
          const float bb = HAS_BIAS ? bias[col] : 0.f;
#pragma unroll
          for (int r = 0; r < 4; ++r) {
            float val = acc[mq][nq][mi][ni][r] * alpha + bb;
            if (GELU) val = 0.5f * val * (1.f + erff(val * 0.70710678118654752f));
            if (HAS_RES) val += res[(size_t)(row + r) * N + col];
            const size_t idx = cb + (size_t)(row + r) * N + col;
            if (OUT_BF16) Cb[idx] = __float2bfloat16(val);
            else Cf[idx] = val;
            if (VTR) {
              if (col >= 2048) {  // V cols: also write V^T [b][col-2048][row%S]
                const int rr = row + r;
                vtr[(((size_t)(rr >> 11) << 10) + (col - 2048)) * 2048 + (rr & 2047)] =
                    __float2bfloat16(val);
              }
            }
          }
        }
      }
}

extern "C" void kernel_launch(void* const* d_in, const int* in_sizes, int n_in,
                              void* d_out, int out_size, void* d_ws, size_t ws_size,
                              hipStream_t stream) {
  const int B = 4, S = 2048, D = 1024, DFF = 4096;
  const int M = B * S;
  const float* x   = (const float*)d_in[0];
  const float* wq  = (const float*)d_in[1];
  const float* bq  = (const float*)d_in[2];
  const float* wk  = (const float*)d_in[3];
  const float* bk  = (const float*)d_in[4];
  const float* wv  = (const float*)d_in[5];
  const float* bv  = (const float*)d_in[6];
  const float* wo  = (const float*)d_in[7];
  const float* bo  = (const float*)d_in[8];
  const float* w1  = (const float*)d_in[9];
  const float* b1  = (const float*)d_in[10];
  const float* w2  = (const float*)d_in[11];
  const float* b2  = (const float*)d_in[12];
  const float* g1  = (const float*)d_in[13];
  const float* be1 = (const float*)d_in[14];
  const float* g2  = (const float*)d_in[15];
  const float* be2 = (const float*)d_in[16];
  float* out = (float*)d_out;

  // workspace arena:
  //  0-6 wqkvT  6-8 woT  8-16 w1T  16-24 w2T  24 bqkv  25-41 h (bf16 MxD)
  //  41-89 qkv (bf16 Mx3072) / later hidden (bf16 MxDFF, 41-105)
  //  89-105 vT [4][D][S] bf16 (written by QKV epilogue)
  //  105+  scores fp32, chunk*16MB
  char* wsb = (char*)d_ws;
  const size_t MB1 = 1ull << 20;
  bf16* wqkvT = (bf16*)(wsb + 0 * MB1);
  bf16* woT   = (bf16*)(wsb + 6 * MB1);
  bf16* w1T   = (bf16*)(wsb + 8 * MB1);
  bf16* w2T   = (bf16*)(wsb + 16 * MB1);
  float* bqkv = (float*)(wsb + 24 * MB1);
  bf16* h     = (bf16*)(wsb + 25 * MB1);
  bf16* qkv   = (bf16*)(wsb + 41 * MB1);
  bf16* hidden = (bf16*)(wsb + 41 * MB1);
  bf16* vTall = (bf16*)(wsb + 89 * MB1);
  float* sc   = (float*)(wsb + 105 * MB1);

  int chunk = 1;
  if (ws_size > 105 * MB1) {
    size_t c = (ws_size - 105 * MB1) / (16 * MB1);
    chunk = (int)(c > 4 ? 4 : (c < 1 ? 1 : c));
  }

  // merged weight transpose + bias concat + LN1 (one dispatch)
  prep_kernel<<<14337, 256, 0, stream>>>(
      wq, wk, wv, wo, w1, w2, wqkvT, woT, w1T, w2T, bq, bk, bv, bqkv,
      x, g1, be1, h);

  // qkv = h @ [wq|wk|wv] + biases; V cols also emitted transposed into vTall
  gemm7<2, true, true, false, false, true><<<24 * 32, 512, 0, stream>>>(
      h, D, 0, wqkvT, D, 0, qkv, 0, bqkv, nullptr, vTall, 3072, D, 1.f, 24, 32);

  for (int b0 = 0; b0 < B; b0 += chunk) {
    int c = (B - b0 < chunk) ? (B - b0) : chunk;
    // scores = q @ k^T * 0.125 (fp32)
    gemm7<4, false, false, false, false, false><<<64 * c, 512, 0, stream>>>(
        qkv + (size_t)b0 * S * 3072, 3072, (size_t)S * 3072,
        qkv + (size_t)b0 * S * 3072 + 1024, 3072, (size_t)S * 3072,
        sc, (size_t)S * S, nullptr, nullptr, nullptr, S, D, 0.125f, 8, 8);
    softmax_wave<<<c * S / 4, 256, 0, stream>>>(sc);
    // ctx = probs @ vT^T (probs bf16 in-place over fp32 rows, pitch 2S)
    gemm7<2, true, false, false, false, false><<<64 * c, 512, 0, stream>>>(
        (const bf16*)sc, 2 * S, (size_t)S * 2 * S,
        vTall + (size_t)b0 * D * S, S, (size_t)D * S,
        h + (size_t)b0 * S * D, (size_t)S * D, nullptr, nullptr, nullptr, D, S, 1.f, 8, 8);
  }

  // x2 = ctx @ wo + bo + x -> d_out (fp32)
  gemm7<2, false, true, true, false, false><<<8 * 32, 512, 0, stream>>>(
      h, D, 0, woT, D, 0, out, 0, bo, x, nullptr, D, D, 1.f, 8, 32);

  // h = LN2(x2)  (wave-per-row, 4 rows/block)
  ln_wave<<<M / 4, 256, 0, stream>>>(out, g2, be2, h);

  // hidden = gelu(h @ w1 + b1)
  gemm7<4, true, true, false, true, false><<<16 * 32, 512, 0, stream>>>(
      h, D, 0, w1T, D, 0, hidden, 0, b1, nullptr, nullptr, DFF, D, 1.f, 16, 32);

  // out = hidden @ w2 + b2 + x2 (in-place residual)
  gemm7<2, false, true, true, false, false><<<8 * 32, 512, 0, stream>>>(
      hidden, DFF, 0, w2T, DFF, 0, out, 0, b2, out, nullptr, D, DFF, 1.f, 8, 32);
}